// Round 6
// baseline (266.070 us; speedup 1.0000x reference)
//
#include <hip/hip_runtime.h>

// Problem constants (from setup_inputs)
#define NB 8
#define NC 3
#define NT 32
#define NH 224
#define NW 224
#define DIFF 16
#define INV_SCALE (224.0f / 240.0f)   // in/out = 14/15

#define TILE_ROWS 16
#define TILES_PER_FRAME (NH / TILE_ROWS)   // 14
#define NFRAMES (NB * NC * NT)             // 768
#define PAIRS (NW / 2)                     // 112 column pairs
#define ROWG (TILE_ROWS / 2)               // 8 rows per thread

// 16B loads at arbitrary 4B alignment (global_load_dwordx4 only needs dword align)
typedef float float4a __attribute__((ext_vector_type(4), aligned(4)));

// 3-cndmask select; r is loop-invariant so the compares hoist out of the row loop
__device__ __forceinline__ float pick4(float4a v, int r) {
    float a = (r == 1) ? v.y : v.x;
    a = (r == 2) ? v.z : a;
    a = (r == 3) ? v.w : a;
    return a;
}

// R6: width theory. R3/R5 showed VMEM *count* (80 vs 50 instrs) doesn't move
// time; every ~80us version used 4B/lane requests. Fills hit 6.4 TB/s with
// dwordx4. So: one dwordx4 per row covers all 4 horizontal taps of a column
// pair (step 14/15 -> span <= base+3), float2 stores, vertical register carry
// of the PICKED scalars -> lerp chain is bit-identical to R5 (absmax safe).
// No LDS, no barriers, no cross-lane ops.
__global__ __launch_bounds__(224) void shake_crop_vec_kernel(
    const float* __restrict__ video,
    const int* __restrict__ shake_h,
    const int* __restrict__ shake_w,
    float* __restrict__ out)
{
    const int tid  = threadIdx.x;
    const int f    = blockIdx.x / TILES_PER_FRAME;   // frame index (b*C+c)*T + t
    const int tile = blockIdx.x - f * TILES_PER_FRAME;
    const int t    = f % NT;
    const int sh   = shake_h[t];                     // block-uniform -> scalar
    const int sw   = shake_w[t];
    const int ybase = tile * TILE_ROWS;
    const int p = tid % PAIRS;                       // column pair index
    const int g = tid / PAIRS;                       // row group 0/1

    // Horizontal weights for the two columns (loop-invariant)
    int x0j[2], x1j[2]; float fxj[2];
    #pragma unroll
    for (int j = 0; j < 2; ++j) {
        int xo = p * 2 + j;
        float ix = fminf(fmaxf((xo + sw + 0.5f) * INV_SCALE - 0.5f, 0.0f), (float)(NW - 1));
        x0j[j] = (int)ix;
        fxj[j] = ix - (float)x0j[j];
        x1j[j] = min(x0j[j] + 1, NW - 1);
    }
    // One dwordx4 at 'base' covers floats base..base+3 (in-row: base <= 220).
    // Proof of cover: x0j[1] <= x0j[0]+1, x1j[1] <= x0j[0]+2 <= base+3; at the
    // right edge (base clamped to 220) all taps are <= 223 = base+3.
    const int base = min(x0j[0], NW - 4);
    const int r00 = x0j[0] - base, r01 = x1j[0] - base;   // all in [0,3]
    const int r10 = x0j[1] - base, r11 = x1j[1] - base;

    const float* frame = video + (size_t)f * (NH * NW);
    float2* orow = (float2*)(out + (size_t)f * (NH * NW)
                                 + (size_t)(ybase + g * ROWG) * NW + p * 2);
    const int ys = ybase + g * ROWG + sh;

    // Prologue: load + pick the top-row taps of the first output row
    float iyp = fminf(fmaxf((ys + 0.5f) * INV_SCALE - 0.5f, 0.0f), (float)(NH - 1));
    const int pY0_init = (int)iyp;
    float4a pr = *(const float4a*)(frame + pY0_init * NW + base);
    // carried TOP taps (row pY0) and BOTTOM taps (row pY1)
    float t00 = pick4(pr, r00), t01 = pick4(pr, r01);
    float t10 = pick4(pr, r10), t11 = pick4(pr, r11);
    float b00 = 0.f, b01 = 0.f, b10 = 0.f, b11 = 0.f;
    int pY1 = -1;

    #pragma unroll
    for (int ry = 0; ry < ROWG; ++ry) {
        float iy = fminf(fmaxf((ys + ry + 0.5f) * INV_SCALE - 0.5f, 0.0f), (float)(NH - 1));
        int   y0 = (int)iy;            // uniform, monotone, step <= 1
        float fy = iy - (float)y0;
        int   y1 = min(y0 + 1, NH - 1);

        // Top taps: advance (y0==pY1) -> carried bottoms; else carried tops.
        const bool adv = (y0 == pY1);
        float v00a = adv ? b00 : t00, v01a = adv ? b01 : t01;
        float v10a = adv ? b10 : t10, v11a = adv ? b11 : t11;

        // Bottom row: ONE dwordx4 + 4 picks (replaces 2 divergent gathers)
        float4a bot = *(const float4a*)(frame + y1 * NW + base);
        float w00 = pick4(bot, r00), w01 = pick4(bot, r01);
        float w10 = pick4(bot, r10), w11 = pick4(bot, r11);

        // Bit-identical lerp chain (same order as all passing versions)
        float top0 = v00a + fxj[0] * (v01a - v00a);
        float bot0 = w00  + fxj[0] * (w01  - w00);
        float o0   = top0 + fy * (bot0 - top0);
        float top1 = v10a + fxj[1] * (v11a - v10a);
        float bot1 = w10  + fxj[1] * (w11  - w10);
        float o1   = top1 + fy * (bot1 - top1);

        float2 res;
        res.x = fminf(fmaxf(o0, 0.0f), 1.0f);
        res.y = fminf(fmaxf(o1, 0.0f), 1.0f);
        orow[ry * (NW / 2)] = res;     // 8B/lane, contiguous across the wave

        // carry
        t00 = v00a; t01 = v01a; t10 = v10a; t11 = v11a;
        b00 = w00;  b01 = w01;  b10 = w10;  b11 = w11;
        pY1 = y1;
    }
}

extern "C" void kernel_launch(void* const* d_in, const int* in_sizes, int n_in,
                              void* d_out, int out_size, void* d_ws, size_t ws_size,
                              hipStream_t stream) {
    const float* video   = (const float*)d_in[0];
    const int*   shake_h = (const int*)d_in[1];
    const int*   shake_w = (const int*)d_in[2];
    float*       out     = (float*)d_out;

    const int grid = NFRAMES * TILES_PER_FRAME;   // 10752 blocks
    shake_crop_vec_kernel<<<grid, 224, 0, stream>>>(video, shake_h, shake_w, out);
}